// Round 2
// baseline (458.694 us; speedup 1.0000x reference)
//
#include <hip/hip_runtime.h>

#define IN_DIM 4096
#define OUT_DIM 4096
#define BATCH 16384

typedef float fx4 __attribute__((ext_vector_type(4)));
typedef int ix4 __attribute__((ext_vector_type(4)));

// ---------------------------------------------------------------------------
// Kernel 1: detect idx dtype. Reference declares int64, but JAX without x64
// demotes to int32 and the harness maps "integer -> const int*". We decide at
// runtime: interpret the idx_a buffer as u32 words; if all odd words among the
// first 4096 are zero, it's little-endian int64 (high halves of values <4096).
// A true int32 array of random values in [0,4096) has ~0 probability of that.
// Reads at most 4096 words = 16 KiB, safe under both interpretations.
// ---------------------------------------------------------------------------
__global__ void detect_kernel(const unsigned int* __restrict__ idx_raw,
                              int* __restrict__ flag) {
    __shared__ unsigned int red[256];
    unsigned int v = 0;
    for (int i = threadIdx.x; i < 2048; i += 256) v |= idx_raw[2 * i + 1];
    red[threadIdx.x] = v;
    __syncthreads();
    for (int s = 128; s > 0; s >>= 1) {
        if ((int)threadIdx.x < s) red[threadIdx.x] |= red[threadIdx.x + s];
        __syncthreads();
    }
    if (threadIdx.x == 0) *flag = (red[0] == 0u) ? 1 : 0;  // 1 => int64
}

// ---------------------------------------------------------------------------
// Kernel 2: per-output-column coefficients.
//   p = softmax(weights[j, 0:16]);  coef[j, c] = sum_k p[k] * G[k][c]
// Stored SoA (c0,c1,c2,c3 arrays) so the main kernel loads them as coalesced
// float4s. Indices packed ia | (ib<<16) (both < 4096, fit in 12 bits).
// ---------------------------------------------------------------------------
__global__ __launch_bounds__(256) void coef_kernel(
    const float* __restrict__ weights,
    const void* __restrict__ idx_a_raw,
    const void* __restrict__ idx_b_raw,
    const int* __restrict__ flag,
    float* __restrict__ c0o, float* __restrict__ c1o,
    float* __restrict__ c2o, float* __restrict__ c3o,
    int* __restrict__ pidx_out) {
    const int j = blockIdx.x * 256 + threadIdx.x;
    if (j >= OUT_DIM) return;

    float w[16];
    const fx4* wp = (const fx4*)(weights + (size_t)j * 16);
#pragma unroll
    for (int q = 0; q < 4; q++) {
        fx4 v = wp[q];
#pragma unroll
        for (int r = 0; r < 4; r++) w[4 * q + r] = v[r];
    }
    float m = w[0];
#pragma unroll
    for (int k = 1; k < 16; k++) m = fmaxf(m, w[k]);
    float s = 0.f;
#pragma unroll
    for (int k = 0; k < 16; k++) { w[k] = expf(w[k] - m); s += w[k]; }
    const float inv = 1.f / s;

    constexpr float G[16][4] = {
        {0, 0, 0, 0},  {0, 0, 0, 1},  {0, 1, 0, -1},  {0, 1, 0, 0},
        {0, 0, 1, -1}, {0, 0, 1, 0},  {0, 1, 1, -2},  {0, 1, 1, -1},
        {1, -1, -1, 1},{1, -1, -1, 2},{1, 0, -1, 0},  {1, 0, -1, 1},
        {1, -1, 0, 0}, {1, -1, 0, 1}, {1, 0, 0, -1},  {1, 0, 0, 0}};
    float c0 = 0.f, c1 = 0.f, c2 = 0.f, c3 = 0.f;
#pragma unroll
    for (int k = 0; k < 16; k++) {
        c0 += w[k] * G[k][0];
        c1 += w[k] * G[k][1];
        c2 += w[k] * G[k][2];
        c3 += w[k] * G[k][3];
    }
    c0o[j] = c0 * inv;
    c1o[j] = c1 * inv;
    c2o[j] = c2 * inv;
    c3o[j] = c3 * inv;

    int ia, ib;
    if (*flag) {
        ia = (int)((const long long*)idx_a_raw)[j];
        ib = (int)((const long long*)idx_b_raw)[j];
    } else {
        ia = ((const int*)idx_a_raw)[j];
        ib = ((const int*)idx_b_raw)[j];
    }
    pidx_out[j] = (ia & 0xFFFF) | (ib << 16);
}

// ---------------------------------------------------------------------------
// Kernel 3: main streaming kernel. One block per batch row.
//  - Stage the 16 KiB x row into LDS via coalesced nontemporal float4 loads
//    (x is read exactly once -> bypass cache, keep L2 for the coef tables).
//  - Each thread computes 16 output columns as 4 groups of 4 consecutive
//    columns; coef/idx loads and y stores are coalesced float4/int4.
//  - a,b gathers hit LDS (random banks; cheap vs the HBM floor).
// ---------------------------------------------------------------------------
__global__ __launch_bounds__(256) void logic_main(
    const float* __restrict__ x,
    const float* __restrict__ c0a, const float* __restrict__ c1a,
    const float* __restrict__ c2a, const float* __restrict__ c3a,
    const int* __restrict__ pidx,
    float* __restrict__ y) {
    __shared__ float xrow[IN_DIM];
    const int row = blockIdx.x;
    const int t = (int)threadIdx.x;

    const fx4* xr = (const fx4*)(x + (size_t)row * IN_DIM);
#pragma unroll
    for (int k = 0; k < IN_DIM / 4 / 256; k++) {
        fx4 v = __builtin_nontemporal_load(&xr[t + k * 256]);
        ((fx4*)xrow)[t + k * 256] = v;
    }
    __syncthreads();

    fx4* yr = (fx4*)(y + (size_t)row * OUT_DIM);
    const fx4* c0v = (const fx4*)c0a;
    const fx4* c1v = (const fx4*)c1a;
    const fx4* c2v = (const fx4*)c2a;
    const fx4* c3v = (const fx4*)c3a;
    const ix4* pv = (const ix4*)pidx;

#pragma unroll
    for (int g = 0; g < OUT_DIM / 4 / 256; g++) {
        const int j4 = g * 256 + t;  // float4-group index (4 consecutive cols)
        const fx4 C0 = c0v[j4];
        const fx4 C1 = c1v[j4];
        const fx4 C2 = c2v[j4];
        const fx4 C3 = c3v[j4];
        const ix4 P = pv[j4];

        fx4 out;
#pragma unroll
        for (int r = 0; r < 4; r++) {
            const int p = P[r];
            const float a = xrow[p & 0xFFFF];
            const float b = xrow[(p >> 16) & 0xFFFF];
            out[r] = C0[r] + C1[r] * a + C2[r] * b + C3[r] * (a * b);
        }
        __builtin_nontemporal_store(out, &yr[j4]);
    }
}

// ---------------------------------------------------------------------------
// Launch. ws layout: [0,4) flag | [256, 256+64Ki) c0..c3 | then pidx (16 KiB).
// Total ws needed: 256 + 5*16384*4 = 82176 bytes.
// ---------------------------------------------------------------------------
extern "C" void kernel_launch(void* const* d_in, const int* in_sizes, int n_in,
                              void* d_out, int out_size, void* d_ws, size_t ws_size,
                              hipStream_t stream) {
    const float* x       = (const float*)d_in[0];
    const float* weights = (const float*)d_in[1];
    const void*  idx_a   = d_in[2];
    const void*  idx_b   = d_in[3];
    float* y = (float*)d_out;

    char* ws = (char*)d_ws;
    int*   flag = (int*)ws;
    float* c0   = (float*)(ws + 256);
    float* c1   = c0 + OUT_DIM;
    float* c2   = c1 + OUT_DIM;
    float* c3   = c2 + OUT_DIM;
    int*   pidx = (int*)(c3 + OUT_DIM);

    hipLaunchKernelGGL(detect_kernel, dim3(1), dim3(256), 0, stream,
                       (const unsigned int*)idx_a, flag);
    hipLaunchKernelGGL(coef_kernel, dim3(OUT_DIM / 256), dim3(256), 0, stream,
                       weights, idx_a, idx_b, flag, c0, c1, c2, c3, pidx);
    hipLaunchKernelGGL(logic_main, dim3(BATCH), dim3(256), 0, stream,
                       x, c0, c1, c2, c3, pidx, y);
}

// Round 3
// 436.990 us; speedup vs baseline: 1.0497x; 1.0497x over previous
//
#include <hip/hip_runtime.h>

#define IN_DIM 4096
#define OUT_DIM 4096
#define BATCH 16384
#define ROWS_PER_BLOCK 8
#define NBLK (BATCH / ROWS_PER_BLOCK) /* 2048 */
#define NT 512

typedef float fx4 __attribute__((ext_vector_type(4)));
typedef int ix4 __attribute__((ext_vector_type(4)));

// ---------------------------------------------------------------------------
// Kernel 1: detect idx dtype (int64 vs int32), as before. OR of odd u32 words
// over the first 4096 words == 0  =>  little-endian int64 with values < 4096.
// ---------------------------------------------------------------------------
__global__ void detect_kernel(const unsigned int* __restrict__ idx_raw,
                              int* __restrict__ flag) {
    __shared__ unsigned int red[256];
    unsigned int v = 0;
    for (int i = threadIdx.x; i < 2048; i += 256) v |= idx_raw[2 * i + 1];
    red[threadIdx.x] = v;
    __syncthreads();
    for (int s = 128; s > 0; s >>= 1) {
        if ((int)threadIdx.x < s) red[threadIdx.x] |= red[threadIdx.x + s];
        __syncthreads();
    }
    if (threadIdx.x == 0) *flag = (red[0] == 0u) ? 1 : 0;  // 1 => int64
}

// ---------------------------------------------------------------------------
// Kernel 2: softmax(weights) @ G -> SoA c0..c3 + packed indices (ia | ib<<16).
// ---------------------------------------------------------------------------
__global__ __launch_bounds__(256) void coef_kernel(
    const float* __restrict__ weights,
    const void* __restrict__ idx_a_raw,
    const void* __restrict__ idx_b_raw,
    const int* __restrict__ flag,
    float* __restrict__ c0o, float* __restrict__ c1o,
    float* __restrict__ c2o, float* __restrict__ c3o,
    int* __restrict__ pidx_out) {
    const int j = blockIdx.x * 256 + threadIdx.x;
    if (j >= OUT_DIM) return;

    float w[16];
    const fx4* wp = (const fx4*)(weights + (size_t)j * 16);
#pragma unroll
    for (int q = 0; q < 4; q++) {
        fx4 v = wp[q];
#pragma unroll
        for (int r = 0; r < 4; r++) w[4 * q + r] = v[r];
    }
    float m = w[0];
#pragma unroll
    for (int k = 1; k < 16; k++) m = fmaxf(m, w[k]);
    float s = 0.f;
#pragma unroll
    for (int k = 0; k < 16; k++) { w[k] = expf(w[k] - m); s += w[k]; }
    const float inv = 1.f / s;

    constexpr float G[16][4] = {
        {0, 0, 0, 0},  {0, 0, 0, 1},  {0, 1, 0, -1},  {0, 1, 0, 0},
        {0, 0, 1, -1}, {0, 0, 1, 0},  {0, 1, 1, -2},  {0, 1, 1, -1},
        {1, -1, -1, 1},{1, -1, -1, 2},{1, 0, -1, 0},  {1, 0, -1, 1},
        {1, -1, 0, 0}, {1, -1, 0, 1}, {1, 0, 0, -1},  {1, 0, 0, 0}};
    float c0 = 0.f, c1 = 0.f, c2 = 0.f, c3 = 0.f;
#pragma unroll
    for (int k = 0; k < 16; k++) {
        c0 += w[k] * G[k][0];
        c1 += w[k] * G[k][1];
        c2 += w[k] * G[k][2];
        c3 += w[k] * G[k][3];
    }
    c0o[j] = c0 * inv;
    c1o[j] = c1 * inv;
    c2o[j] = c2 * inv;
    c3o[j] = c3 * inv;

    int ia, ib;
    if (*flag) {
        ia = (int)((const long long*)idx_a_raw)[j];
        ib = (int)((const long long*)idx_b_raw)[j];
    } else {
        ia = ((const int*)idx_a_raw)[j];
        ib = ((const int*)idx_b_raw)[j];
    }
    pidx_out[j] = (ia & 0xFFFF) | (ib << 16);
}

// ---------------------------------------------------------------------------
// Kernel 3: streaming pipeline. 2048 blocks x 8 rows, 512 threads.
//  - coef+idx cached in registers once per block (no per-row L2 re-read)
//  - 2-row-deep register prefetch (PA/PB), double-buffered LDS rows
//  - raw s_barrier with lgkmcnt(0) only: vmcnt never drained in the loop,
//    so prefetch loads stay in flight across barriers
// ---------------------------------------------------------------------------
#define BARRIER()                                             \
    do {                                                      \
        asm volatile("s_waitcnt lgkmcnt(0)" ::: "memory");    \
        __builtin_amdgcn_s_barrier();                         \
        __builtin_amdgcn_sched_barrier(0);                    \
    } while (0)

__global__ __launch_bounds__(NT, 4) void logic_main(
    const float* __restrict__ x,
    const float* __restrict__ c0a, const float* __restrict__ c1a,
    const float* __restrict__ c2a, const float* __restrict__ c3a,
    const int* __restrict__ pidx,
    float* __restrict__ y) {
    __shared__ float xbuf0[IN_DIM];
    __shared__ float xbuf1[IN_DIM];
    const int t = (int)threadIdx.x;
    const int rowbase = (int)blockIdx.x * ROWS_PER_BLOCK;

    // ---- cache coefs + packed idx in registers (block-lifetime) ----
    fx4 C0[2], C1[2], C2[2], C3[2];
    ix4 PK[2];
    {
        const fx4* c0v = (const fx4*)c0a;
        const fx4* c1v = (const fx4*)c1a;
        const fx4* c2v = (const fx4*)c2a;
        const fx4* c3v = (const fx4*)c3a;
        const ix4* pv = (const ix4*)pidx;
#pragma unroll
        for (int g = 0; g < 2; ++g) {
            const int j4 = g * NT + t;
            C0[g] = c0v[j4];
            C1[g] = c1v[j4];
            C2[g] = c2v[j4];
            C3[g] = c3v[j4];
            PK[g] = pv[j4];
        }
    }

    fx4 pa0, pa1, pb0, pb1;  // two in-flight rows (even->PA, odd->PB)

#define LOADROW(P0, P1, r)                                                    \
    do {                                                                      \
        const fx4* src_ = (const fx4*)(x + (size_t)(rowbase + (r)) * IN_DIM); \
        P0 = __builtin_nontemporal_load(&src_[t]);                            \
        P1 = __builtin_nontemporal_load(&src_[t + NT]);                       \
    } while (0)

#define STAGE(buf, P0, P1)                \
    do {                                  \
        ((fx4*)(buf))[t] = P0;            \
        ((fx4*)(buf))[t + NT] = P1;       \
    } while (0)

    // prologue: rows 0,1 in flight; stage row 0; start row 2
    LOADROW(pa0, pa1, 0);
    LOADROW(pb0, pb1, 1);
    STAGE(xbuf0, pa0, pa1);  // compiler inserts vmcnt wait for pa
    LOADROW(pa0, pa1, 2);
    BARRIER();

#pragma unroll
    for (int r = 0; r < ROWS_PER_BLOCK; ++r) {
        const float* cbuf = (r & 1) ? xbuf1 : xbuf0;
        float* nbuf = (r & 1) ? xbuf0 : xbuf1;

        // ---- compute row r from cbuf ----
        {
            fx4* yr = (fx4*)(y + (size_t)(rowbase + r) * OUT_DIM);
#pragma unroll
            for (int g = 0; g < 2; ++g) {
                const ix4 P = PK[g];
                fx4 out;
#pragma unroll
                for (int q = 0; q < 4; ++q) {
                    const int p = P[q];
                    const float a = cbuf[p & 0xFFFF];
                    const float b = cbuf[(p >> 16) & 0xFFFF];
                    out[q] = C0[g][q] + C1[g][q] * a + C2[g][q] * b +
                             C3[g][q] * (a * b);
                }
                __builtin_nontemporal_store(out, &yr[g * NT + t]);
            }
        }

        // ---- stage row r+1 (arrived ~2 iterations ago), refill prefetch ----
        if (r + 1 < ROWS_PER_BLOCK) {
            if ((r + 1) & 1) {
                STAGE(nbuf, pb0, pb1);
            } else {
                STAGE(nbuf, pa0, pa1);
            }
            if (r + 3 < ROWS_PER_BLOCK) {
                if ((r + 3) & 1) {
                    LOADROW(pb0, pb1, r + 3);
                } else {
                    LOADROW(pa0, pa1, r + 3);
                }
            }
            BARRIER();
        }
    }
#undef LOADROW
#undef STAGE
}

// ---------------------------------------------------------------------------
// Launch. ws layout: [0,4) flag | [256,...) c0,c1,c2,c3 | pidx.
// Total ws needed: 256 + 5*4096*4 = 82176 bytes.
// ---------------------------------------------------------------------------
extern "C" void kernel_launch(void* const* d_in, const int* in_sizes, int n_in,
                              void* d_out, int out_size, void* d_ws, size_t ws_size,
                              hipStream_t stream) {
    const float* x       = (const float*)d_in[0];
    const float* weights = (const float*)d_in[1];
    const void*  idx_a   = d_in[2];
    const void*  idx_b   = d_in[3];
    float* y = (float*)d_out;

    char* ws = (char*)d_ws;
    int*   flag = (int*)ws;
    float* c0   = (float*)(ws + 256);
    float* c1   = c0 + OUT_DIM;
    float* c2   = c1 + OUT_DIM;
    float* c3   = c2 + OUT_DIM;
    int*   pidx = (int*)(c3 + OUT_DIM);

    hipLaunchKernelGGL(detect_kernel, dim3(1), dim3(256), 0, stream,
                       (const unsigned int*)idx_a, flag);
    hipLaunchKernelGGL(coef_kernel, dim3(OUT_DIM / 256), dim3(256), 0, stream,
                       weights, idx_a, idx_b, flag, c0, c1, c2, c3, pidx);
    hipLaunchKernelGGL(logic_main, dim3(NBLK), dim3(NT), 0, stream,
                       x, c0, c1, c2, c3, pidx, y);
}